// Round 1
// baseline (707.211 us; speedup 1.0000x reference)
//
#include <hip/hip_runtime.h>
#include <math.h>

// Problem constants (from reference setup_inputs): B=4,H=8,S=4096,D=128,BT=64
#define Gp  32      // B*H
#define Sp  4096
#define Dp  128
#define BTp 64
#define NCp 64      // S/BT

// ---------------------------------------------------------------------------
// Kernel A: per-chunk intra output + per-chunk state contribution (upd)
// grid = G*NC = 2048 blocks, 512 threads
// ---------------------------------------------------------------------------
__global__ __launch_bounds__(512) void gdn_intra(
    const float* __restrict__ q, const float* __restrict__ k,
    const float* __restrict__ v, const float* __restrict__ beta,
    float* __restrict__ out, float* __restrict__ upd,
    float* __restrict__ tot_buf, float* __restrict__ dfs_buf)
{
    const int blk = blockIdx.x;
    const int g = blk >> 6;       // / NC
    const int c = blk & 63;       // % NC
    const int tid = threadIdx.x;
    const size_t base = ((size_t)g * Sp + (size_t)c * BTp) * Dp;

    __shared__ float s_q[BTp * Dp];         // 32 KB, broadcast reads
    __shared__ float s_k[BTp * (Dp + 1)];   // padded stride 129 -> conflict-free lane=j reads
    __shared__ float s_v[BTp * Dp];         // lane=d reads (2-way, free)
    __shared__ float s_qk[BTp * (BTp + 1)]; // 16.25 KB
    __shared__ float s_cum[BTp];
    __shared__ float s_dte[BTp];

    for (int idx = tid; idx < BTp * Dp; idx += 512) {
        s_q[idx] = q[base + idx];
        s_v[idx] = v[base + idx];
        const int row = idx >> 7, col = idx & 127;
        s_k[row * (Dp + 1) + col] = k[base + idx];
    }
    if (tid < BTp)
        s_cum[tid] = logf(beta[(size_t)g * Sp + (size_t)c * BTp + tid] + 1e-6f);
    __syncthreads();
    if (tid == 0) {  // serial 64-element cumsum: negligible
        float acc = 0.f;
        for (int i = 0; i < BTp; ++i) { acc += s_cum[i]; s_cum[i] = acc; }
    }
    __syncthreads();
    const float tot = s_cum[BTp - 1];
    if (tid < BTp) {
        s_dte[tid] = expf(tot - s_cum[tid]);                       // decay_to_end
        dfs_buf[(size_t)g * Sp + (size_t)c * BTp + tid] = expf(s_cum[tid]); // decay_from_start
    }
    if (tid == 0) tot_buf[g * NCp + c] = tot;
    __syncthreads();

    // qk[i][j] = dot(q_i, k_j) * decay_mask
    {
        const int j = tid & 63;
        const int ig = tid >> 6;             // 0..7, wave-uniform
        const float cj = s_cum[j];
        for (int r = 0; r < 8; ++r) {
            const int i = ig * 8 + r;
            float acc = 0.f;
            #pragma unroll
            for (int d0 = 0; d0 < Dp; ++d0)
                acc += s_q[i * Dp + d0] * s_k[j * (Dp + 1) + d0];
            const float dm = (i >= j) ? expf(s_cum[i] - cj) : 0.f;
            s_qk[i * (BTp + 1) + j] = acc * dm;
        }
    }
    __syncthreads();

    // out_intra[i][d] = sum_j qk[i][j] * v[j][d]
    {
        const int d = tid & 127;
        const int ig = tid >> 7;             // 0..3, wave-uniform
        float acc[16];
        #pragma unroll
        for (int r = 0; r < 16; ++r) acc[r] = 0.f;
        for (int jj = 0; jj < BTp; ++jj) {
            const float vv = s_v[jj * Dp + d];
            #pragma unroll
            for (int r = 0; r < 16; ++r)
                acc[r] += s_qk[(ig * 16 + r) * (BTp + 1) + jj] * vv;
        }
        #pragma unroll
        for (int r = 0; r < 16; ++r)
            out[base + (size_t)(ig * 16 + r) * Dp + d] = acc[r];
    }

    // upd[d][e] = sum_i k[i][d] * dte[i] * v[i][e]   (no barrier needed: LDS reads only)
    {
        const int e = tid & 127;
        const int dg = tid >> 7;             // 0..3, wave-uniform
        float acc[32];
        #pragma unroll
        for (int r = 0; r < 32; ++r) acc[r] = 0.f;
        for (int i = 0; i < BTp; ++i) {
            const float wv = s_v[i * Dp + e] * s_dte[i];
            #pragma unroll
            for (int r = 0; r < 32; ++r)
                acc[r] += s_k[i * (Dp + 1) + dg * 32 + r] * wv;
        }
        const size_t ub = (size_t)blk * Dp * Dp;
        #pragma unroll
        for (int r = 0; r < 32; ++r)
            upd[ub + (size_t)(dg * 32 + r) * Dp + e] = acc[r];
    }
}

// ---------------------------------------------------------------------------
// Kernel B: sequential inter-chunk scan, elementwise-parallel over the
// 128x128 state. In-place: slot c is read (upd_c) then overwritten with the
// PRE-chunk state S_c (S_0 = 0). grid = G*16 slabs, 256 threads, 4 elem/thread
// ---------------------------------------------------------------------------
__global__ __launch_bounds__(256) void gdn_scan(
    float* __restrict__ upd, const float* __restrict__ tot_buf)
{
    const int g = blockIdx.x >> 4;
    const int slab = blockIdx.x & 15;
    const int tid = threadIdx.x;
    __shared__ float s_e[NCp];
    if (tid < NCp) s_e[tid] = expf(tot_buf[g * NCp + tid]);
    __syncthreads();
    const int off = slab * 1024 + tid;
    const size_t gbase = (size_t)g * NCp * Dp * Dp;
    float st0 = 0.f, st1 = 0.f, st2 = 0.f, st3 = 0.f;
    for (int c = 0; c < NCp; ++c) {
        float* p = upd + gbase + (size_t)c * Dp * Dp + off;
        const float ec = s_e[c];
        const float u0 = p[0], u1 = p[256], u2 = p[512], u3 = p[768];
        p[0] = st0; p[256] = st1; p[512] = st2; p[768] = st3;
        st0 = st0 * ec + u0;
        st1 = st1 * ec + u1;
        st2 = st2 * ec + u2;
        st3 = st3 * ec + u3;
    }
}

// ---------------------------------------------------------------------------
// Kernel C: out[i][d] += dfs[i] * sum_e q[i][e] * S_c[e][d]
// grid = G*NC = 2048 blocks, 512 threads
// ---------------------------------------------------------------------------
__global__ __launch_bounds__(512) void gdn_inter(
    const float* __restrict__ q, const float* __restrict__ state,
    const float* __restrict__ dfs_buf, float* __restrict__ out)
{
    const int blk = blockIdx.x;
    const int g = blk >> 6, c = blk & 63;
    const int tid = threadIdx.x;
    const size_t base = ((size_t)g * Sp + (size_t)c * BTp) * Dp;

    __shared__ float s_S[Dp * Dp];   // 64 KB
    __shared__ float s_q[BTp * Dp];  // 32 KB
    __shared__ float s_dfs[BTp];

    const size_t sb = (size_t)blk * Dp * Dp;
    for (int idx = tid; idx < Dp * Dp; idx += 512) s_S[idx] = state[sb + idx];
    for (int idx = tid; idx < BTp * Dp; idx += 512) s_q[idx] = q[base + idx];
    if (tid < BTp) s_dfs[tid] = dfs_buf[(size_t)g * Sp + (size_t)c * BTp + tid];
    __syncthreads();

    const int d = tid & 127;
    const int ig = tid >> 7;  // 0..3, wave-uniform
    float acc[16];
    #pragma unroll
    for (int r = 0; r < 16; ++r) acc[r] = 0.f;
    for (int e = 0; e < Dp; ++e) {
        const float sv = s_S[e * Dp + d];
        #pragma unroll
        for (int r = 0; r < 16; ++r)
            acc[r] += s_q[(ig * 16 + r) * Dp + e] * sv;
    }
    #pragma unroll
    for (int r = 0; r < 16; ++r) {
        const int i = ig * 16 + r;
        const size_t o = base + (size_t)i * Dp + d;
        out[o] += s_dfs[i] * acc[r];
    }
}

// ---------------------------------------------------------------------------
extern "C" void kernel_launch(void* const* d_in, const int* in_sizes, int n_in,
                              void* d_out, int out_size, void* d_ws, size_t ws_size,
                              hipStream_t stream) {
    const float* q    = (const float*)d_in[0];
    const float* k    = (const float*)d_in[1];
    const float* v    = (const float*)d_in[2];
    const float* beta = (const float*)d_in[3];
    float* out = (float*)d_out;

    // ws layout (floats): upd/state [G*NC*D*D]=33.5M, tot [G*NC], dfs [G*S]
    float* upd     = (float*)d_ws;
    float* tot_buf = upd + (size_t)Gp * NCp * Dp * Dp;
    float* dfs_buf = tot_buf + (size_t)Gp * NCp;

    gdn_intra<<<Gp * NCp, 512, 0, stream>>>(q, k, v, beta, out, upd, tot_buf, dfs_buf);
    gdn_scan<<<Gp * 16, 256, 0, stream>>>(upd, tot_buf);
    gdn_inter<<<Gp * NCp, 512, 0, stream>>>(q, upd, dfs_buf, out);
}

// Round 2
// 349.339 us; speedup vs baseline: 2.0244x; 2.0244x over previous
//
#include <hip/hip_runtime.h>
#include <math.h>

// Problem constants: B=4,H=8,S=4096,D=128,BT=64
#define Gp  32      // B*H
#define Sp  4096
#define Dp  128
#define BTp 64
#define NCp 64      // S/BT

typedef __attribute__((ext_vector_type(8))) short bf16x8;
typedef __attribute__((ext_vector_type(4))) float f32x4;

#define MFMA(a,b,c) __builtin_amdgcn_mfma_f32_16x16x32_bf16((a),(b),(c),0,0,0)

// LDS row strides (bf16 elems), multiples of 8 to keep 16B-aligned frag reads
#define SQK 136   // 64x128 row-major arrays (q,k,state,P-not)
#define STR 72    // 128x64 transposed arrays (vt,kt) and s_P rows

__device__ inline unsigned short f2bf(float x) {
    union { float f; unsigned u; } u; u.f = x;
    unsigned r = u.u + 0x7fffu + ((u.u >> 16) & 1u);  // RNE
    return (unsigned short)(r >> 16);
}
__device__ inline unsigned pack2(float lo, float hi) {
    return (unsigned)f2bf(lo) | ((unsigned)f2bf(hi) << 16);
}

// ---------------------------------------------------------------------------
// Kernel A: intra-chunk output + transposed per-chunk state term (updT).
// One block per chunk, 256 threads = 4 waves.
// ---------------------------------------------------------------------------
__global__ __launch_bounds__(256, 2) void gdn_intra(
    const float* __restrict__ q, const float* __restrict__ k,
    const float* __restrict__ v, const float* __restrict__ beta,
    float* __restrict__ out, float* __restrict__ upd,
    float* __restrict__ tot_buf, float* __restrict__ dfs_buf)
{
    __shared__ unsigned short s_q [64 * SQK];   // q row-major bf16
    __shared__ unsigned short s_k [64 * SQK];   // k row-major bf16
    __shared__ unsigned short s_vt[128 * STR];  // v^T  [d][i]
    __shared__ unsigned short s_kt[128 * STR];  // (k*dte)^T [d][i]
    __shared__ unsigned short s_P [64 * STR];   // masked/decayed P, row-major
    __shared__ float s_cum[64];
    __shared__ float s_dte[64];

    const int blk = blockIdx.x;
    const int g = blk >> 6, c = blk & 63;
    const int tid = threadIdx.x;
    const int lane = tid & 63, w = tid >> 6;
    const int m16 = lane & 15, quad = lane >> 4;
    const size_t base  = ((size_t)g * Sp + (size_t)c * BTp) * Dp;
    const size_t bbase = (size_t)g * Sp + (size_t)c * BTp;

    // wave 0: log-beta inclusive prefix sum + derived decays
    if (w == 0) {
        float x = logf(beta[bbase + lane] + 1e-6f);
        #pragma unroll
        for (int off = 1; off < 64; off <<= 1) {
            float n = __shfl_up(x, off, 64);
            if (lane >= off) x += n;
        }
        s_cum[lane] = x;
        float tot = __shfl(x, 63, 64);
        s_dte[lane] = expf(tot - x);
        dfs_buf[bbase + lane] = expf(x);
        if (lane == 63) tot_buf[g * NCp + c] = tot;
    }

    // q,k -> row-major bf16 (packed pair writes, coalesced float2 reads)
    for (int it = 0; it < 16; ++it) {
        const int p = it * 256 + tid;            // pair 0..4095
        const int i = p >> 6, d = (p & 63) * 2;
        const float2 qv = *(const float2*)(q + base + i * Dp + d);
        const float2 kv = *(const float2*)(k + base + i * Dp + d);
        *(unsigned*)&s_q[i * SQK + d] = pack2(qv.x, qv.y);
        *(unsigned*)&s_k[i * SQK + d] = pack2(kv.x, kv.y);
    }
    // v -> transposed bf16: s_vt[d][i] (row = d, packed i-pairs)
    for (int it = 0; it < 16; ++it) {
        const int u = it * 256 + tid;
        const int d = u & 127, i = (u >> 7) * 2;
        const float v0 = v[base + (size_t)i * Dp + d];
        const float v1 = v[base + (size_t)(i + 1) * Dp + d];
        *(unsigned*)&s_vt[d * STR + i] = pack2(v0, v1);
    }
    __syncthreads();   // s_dte visible to all; q/k/vt staged

    // k*dte -> transposed bf16 (re-reads k: L1/L2 hit, same block)
    for (int it = 0; it < 16; ++it) {
        const int u = it * 256 + tid;
        const int d = u & 127, i = (u >> 7) * 2;
        const float k0 = k[base + (size_t)i * Dp + d] * s_dte[i];
        const float k1 = k[base + (size_t)(i + 1) * Dp + d] * s_dte[i + 1];
        *(unsigned*)&s_kt[d * STR + i] = pack2(k0, k1);
    }
    __syncthreads();

    // ---- GEMM1: qk = Q @ K^T  (wave w: rows 16w..16w+15, all 64 cols) ----
    {
        f32x4 accP[4] = {};
        const unsigned short* arow = &s_q[(16 * w + m16) * SQK + quad * 8];
        #pragma unroll
        for (int ks = 0; ks < 4; ++ks) {
            const bf16x8 af = *(const bf16x8*)(arow + ks * 32);
            #pragma unroll
            for (int nt = 0; nt < 4; ++nt) {
                const bf16x8 bf = *(const bf16x8*)(&s_k[(16 * nt + m16) * SQK + quad * 8 + ks * 32]);
                accP[nt] = MFMA(af, bf, accP[nt]);
            }
        }
        // epilogue: causal mask + decay, store bf16 P
        const int i0 = 16 * w + quad * 4;
        float ci[4];
        #pragma unroll
        for (int r = 0; r < 4; ++r) ci[r] = s_cum[i0 + r];
        #pragma unroll
        for (int nt = 0; nt < 4; ++nt) {
            const int j = 16 * nt + m16;
            const float cj = s_cum[j];
            #pragma unroll
            for (int r = 0; r < 4; ++r) {
                const int i = i0 + r;
                const float pv = (i >= j) ? accP[nt][r] * expf(ci[r] - cj) : 0.f;
                s_P[i * STR + j] = f2bf(pv);
            }
        }
    }

    // ---- GEMM3: updT[e][d] = sum_i v[i][e]*dte[i]*k[i][d]  (A=s_vt, B=s_kt)
    // wave w: rows 32w..32w+31 (2 m-tiles) x all 128 cols (8 n-tiles)
    {
        f32x4 accU[2][8] = {};
        #pragma unroll
        for (int ks = 0; ks < 2; ++ks) {
            bf16x8 af0 = *(const bf16x8*)(&s_vt[(32 * w      + m16) * STR + quad * 8 + ks * 32]);
            bf16x8 af1 = *(const bf16x8*)(&s_vt[(32 * w + 16 + m16) * STR + quad * 8 + ks * 32]);
            #pragma unroll
            for (int nt = 0; nt < 8; ++nt) {
                const bf16x8 bf = *(const bf16x8*)(&s_kt[(16 * nt + m16) * STR + quad * 8 + ks * 32]);
                accU[0][nt] = MFMA(af0, bf, accU[0][nt]);
                accU[1][nt] = MFMA(af1, bf, accU[1][nt]);
            }
        }
        const size_t ub = (size_t)blk * Dp * Dp;
        #pragma unroll
        for (int mt = 0; mt < 2; ++mt) {
            const int e0 = 32 * w + 16 * mt + quad * 4;
            #pragma unroll
            for (int nt = 0; nt < 8; ++nt) {
                const int d = 16 * nt + m16;
                #pragma unroll
                for (int r = 0; r < 4; ++r)
                    upd[ub + (size_t)(e0 + r) * Dp + d] = accU[mt][nt][r];
            }
        }
    }
    __syncthreads();   // s_P ready for all waves

    // ---- GEMM2: out_intra = P @ V  (A=s_P, B=s_vt) ----
    {
        f32x4 accO[8] = {};
        #pragma unroll
        for (int ks = 0; ks < 2; ++ks) {
            const bf16x8 af = *(const bf16x8*)(&s_P[(16 * w + m16) * STR + quad * 8 + ks * 32]);
            #pragma unroll
            for (int nt = 0; nt < 8; ++nt) {
                const bf16x8 bf = *(const bf16x8*)(&s_vt[(16 * nt + m16) * STR + quad * 8 + ks * 32]);
                accO[nt] = MFMA(af, bf, accO[nt]);
            }
        }
        const int i0 = 16 * w + quad * 4;
        #pragma unroll
        for (int nt = 0; nt < 8; ++nt) {
            const int d = 16 * nt + m16;
            #pragma unroll
            for (int r = 0; r < 4; ++r)
                out[base + (size_t)(i0 + r) * Dp + d] = accO[nt][r];
        }
    }
}

// ---------------------------------------------------------------------------
// Kernel B: sequential inter-chunk scan, elementwise over the (transposed)
// 128x128 state. In-place: slot c read (updT_c), overwritten with PRE-state.
// ---------------------------------------------------------------------------
__global__ __launch_bounds__(256) void gdn_scan(
    float* __restrict__ upd, const float* __restrict__ tot_buf)
{
    const int g = blockIdx.x >> 4;
    const int slab = blockIdx.x & 15;
    const int tid = threadIdx.x;
    __shared__ float s_e[NCp];
    if (tid < NCp) s_e[tid] = expf(tot_buf[g * NCp + tid]);
    __syncthreads();
    const int off = slab * 1024 + tid;
    const size_t gbase = (size_t)g * NCp * Dp * Dp;
    float st0 = 0.f, st1 = 0.f, st2 = 0.f, st3 = 0.f;
    for (int c = 0; c < NCp; ++c) {
        float* p = upd + gbase + (size_t)c * Dp * Dp + off;
        const float ec = s_e[c];
        const float u0 = p[0], u1 = p[256], u2 = p[512], u3 = p[768];
        p[0] = st0; p[256] = st1; p[512] = st2; p[768] = st3;
        st0 = st0 * ec + u0;
        st1 = st1 * ec + u1;
        st2 = st2 * ec + u2;
        st3 = st3 * ec + u3;
    }
}

// ---------------------------------------------------------------------------
// Kernel C: out[i][e] += sum_d q[i][d]*dfs[i] * state[d][e], MFMA.
// stateT[e][d] is what's in memory -> B-operand reads are row-major.
// ---------------------------------------------------------------------------
__global__ __launch_bounds__(256, 3) void gdn_inter(
    const float* __restrict__ q, const float* __restrict__ state,
    const float* __restrict__ dfs_buf, float* __restrict__ out)
{
    __shared__ unsigned short s_st[128 * SQK];  // stateT row-major bf16
    __shared__ unsigned short s_q [64 * SQK];   // q*dfs row-major bf16

    const int blk = blockIdx.x;
    const int g = blk >> 6, c = blk & 63;
    const int tid = threadIdx.x;
    const int lane = tid & 63, w = tid >> 6;
    const int m16 = lane & 15, quad = lane >> 4;
    const size_t base  = ((size_t)g * Sp + (size_t)c * BTp) * Dp;
    const size_t bbase = (size_t)g * Sp + (size_t)c * BTp;
    const size_t sb = (size_t)blk * Dp * Dp;

    for (int it = 0; it < 32; ++it) {
        const int p = it * 256 + tid;            // pair 0..8191
        const int e = p >> 6, d = (p & 63) * 2;
        const float2 sv = *(const float2*)(state + sb + e * Dp + d);
        *(unsigned*)&s_st[e * SQK + d] = pack2(sv.x, sv.y);
    }
    for (int it = 0; it < 16; ++it) {
        const int p = it * 256 + tid;
        const int i = p >> 6, d = (p & 63) * 2;
        const float sc = dfs_buf[bbase + i];
        const float2 qv = *(const float2*)(q + base + i * Dp + d);
        *(unsigned*)&s_q[i * SQK + d] = pack2(qv.x * sc, qv.y * sc);
    }
    __syncthreads();

    f32x4 acc[8] = {};
    const unsigned short* ar = &s_q[(16 * w + m16) * SQK + quad * 8];
    #pragma unroll
    for (int ks = 0; ks < 4; ++ks) {
        const bf16x8 af = *(const bf16x8*)(ar + ks * 32);
        #pragma unroll
        for (int nt = 0; nt < 8; ++nt) {
            const bf16x8 bf = *(const bf16x8*)(&s_st[(16 * nt + m16) * SQK + quad * 8 + ks * 32]);
            acc[nt] = MFMA(af, bf, acc[nt]);
        }
    }
    const int i0 = 16 * w + quad * 4;
    #pragma unroll
    for (int nt = 0; nt < 8; ++nt) {
        const int e = 16 * nt + m16;
        #pragma unroll
        for (int r = 0; r < 4; ++r)
            out[base + (size_t)(i0 + r) * Dp + e] += acc[nt][r];
    }
}

// ---------------------------------------------------------------------------
extern "C" void kernel_launch(void* const* d_in, const int* in_sizes, int n_in,
                              void* d_out, int out_size, void* d_ws, size_t ws_size,
                              hipStream_t stream) {
    const float* q    = (const float*)d_in[0];
    const float* k    = (const float*)d_in[1];
    const float* v    = (const float*)d_in[2];
    const float* beta = (const float*)d_in[3];
    float* out = (float*)d_out;

    float* upd     = (float*)d_ws;                           // G*NC*D*D fp32 (updT/stateT)
    float* tot_buf = upd + (size_t)Gp * NCp * Dp * Dp;
    float* dfs_buf = tot_buf + (size_t)Gp * NCp;

    gdn_intra<<<Gp * NCp, 256, 0, stream>>>(q, k, v, beta, out, upd, tot_buf, dfs_buf);
    gdn_scan <<<Gp * 16, 256, 0, stream>>>(upd, tot_buf);
    gdn_inter<<<Gp * NCp, 256, 0, stream>>>(q, upd, dfs_buf, out);
}

// Round 3
// 326.638 us; speedup vs baseline: 2.1651x; 1.0695x over previous
//
#include <hip/hip_runtime.h>
#include <math.h>

// Problem constants: B=4,H=8,S=4096,D=128,BT=64
#define Gp  32      // B*H
#define Sp  4096
#define Dp  128
#define BTp 64
#define NCp 64      // S/BT

typedef __attribute__((ext_vector_type(8))) short bf16x8;
typedef __attribute__((ext_vector_type(4))) float f32x4;

#define MFMA(a,b,c) __builtin_amdgcn_mfma_f32_16x16x32_bf16((a),(b),(c),0,0,0)

#define STR 72    // transposed buffers (vt,kt) and P row stride, bf16 elems

__device__ inline unsigned short f2bf(float x) {
    union { float f; unsigned u; } u; u.f = x;
    unsigned r = u.u + 0x7fffu + ((u.u >> 16) & 1u);  // RNE
    return (unsigned short)(r >> 16);
}
__device__ inline unsigned pack2(float lo, float hi) {
    return (unsigned)f2bf(lo) | ((unsigned)f2bf(hi) << 16);
}
__device__ inline float bflo(unsigned u) { union { unsigned u; float f; } t; t.u = u << 16; return t.f; }
__device__ inline float bfhi(unsigned u) { union { unsigned u; float f; } t; t.u = u & 0xffff0000u; return t.f; }

// ---------------------------------------------------------------------------
// Kernel A: intra-chunk output + transposed per-chunk state term (updT, bf16).
// 256 threads, LDS = 52 KB -> 3 blocks/CU.
// s_k XOR-swizzled: elem (i,d) at i*128 + ((d>>3 ^ (i&15))<<3) + (d&7)
// ---------------------------------------------------------------------------
__global__ __launch_bounds__(256, 3) void gdn_intra(
    const float* __restrict__ q, const float* __restrict__ k,
    const float* __restrict__ v, const float* __restrict__ beta,
    float* __restrict__ out, unsigned short* __restrict__ upd,
    float* __restrict__ tot_buf, float* __restrict__ dfs_buf)
{
    __shared__ unsigned short s_k [64 * 128];   // swizzled; P overlays after GEMM1
    __shared__ unsigned short s_vt[128 * STR];  // v^T  [d][i]
    __shared__ unsigned short s_kt[128 * STR];  // (k*dte)^T [d][i]

    const int blk = blockIdx.x, g = blk >> 6, c = blk & 63;
    const int tid = threadIdx.x, lane = tid & 63, w = tid >> 6;
    const int m16 = lane & 15, quad = lane >> 4;
    const size_t base  = ((size_t)g * Sp + (size_t)c * BTp) * Dp;
    const size_t bbase = (size_t)g * Sp + (size_t)c * BTp;

    // every wave redundantly computes the 64-lane log-beta prefix (no LDS dep)
    float x = logf(beta[bbase + lane] + 1e-6f);
    #pragma unroll
    for (int off = 1; off < 64; off <<= 1) {
        float n = __shfl_up(x, off, 64);
        if (lane >= off) x += n;
    }
    const float tot = __shfl(x, 63, 64);
    const float dte_own = expf(tot - x);          // lane L holds dte[L]
    if (tid < 64) dfs_buf[bbase + lane] = expf(x);
    if (tid == 63) tot_buf[g * NCp + c] = tot;

    // q A-fragments straight from global (wave-exclusive rows 16w..16w+15)
    bf16x8 qf[4];
    {
        const float* qrow = q + base + (size_t)(16 * w + m16) * Dp + quad * 8;
        #pragma unroll
        for (int ks = 0; ks < 4; ++ks) {
            const float4 a = *(const float4*)(qrow + ks * 32);
            const float4 b = *(const float4*)(qrow + ks * 32 + 4);
            union { bf16x8 v; unsigned ui[4]; } t;
            t.ui[0] = pack2(a.x, a.y); t.ui[1] = pack2(a.z, a.w);
            t.ui[2] = pack2(b.x, b.y); t.ui[3] = pack2(b.z, b.w);
            qf[ks] = t.v;
        }
    }

    // stage k -> s_k (swizzled, conflict-free writes & frag reads)
    #pragma unroll 4
    for (int it = 0; it < 16; ++it) {
        const int p = it * 256 + tid;
        const int i = p >> 6, d = (p & 63) * 2;
        const float2 kv = *(const float2*)(k + base + (size_t)i * Dp + d);
        const int ad = i * 128 + ((((d >> 3) ^ (i & 15))) << 3) + (d & 7);
        *(unsigned*)&s_k[ad] = pack2(kv.x, kv.y);
    }
    // stage v^T and (k*dte)^T (k re-read hits L1)
    #pragma unroll 4
    for (int it = 0; it < 16; ++it) {
        const int u = it * 256 + tid;
        const int d = u & 127, i = (u >> 7) * 2;       // i wave-uniform per iter
        const float dte0 = __shfl(dte_own, i, 64);
        const float dte1 = __shfl(dte_own, i + 1, 64);
        const float v0 = v[base + (size_t)i * Dp + d];
        const float v1 = v[base + (size_t)(i + 1) * Dp + d];
        const float k0 = k[base + (size_t)i * Dp + d] * dte0;
        const float k1 = k[base + (size_t)(i + 1) * Dp + d] * dte1;
        *(unsigned*)&s_vt[d * STR + i] = pack2(v0, v1);
        *(unsigned*)&s_kt[d * STR + i] = pack2(k0, k1);
    }
    __syncthreads();

    // ---- GEMM1: P = Q @ K^T, epilogue (mask+decay) kept in registers ----
    float pv[4][4];
    {
        f32x4 accP[4] = {};
        #pragma unroll
        for (int ks = 0; ks < 4; ++ks) {
            #pragma unroll
            for (int nt = 0; nt < 4; ++nt) {
                const int j = 16 * nt + m16;
                const bf16x8 bf = *(const bf16x8*)&s_k[j * 128 + (((quad + 4 * ks) ^ m16) << 3)];
                accP[nt] = MFMA(qf[ks], bf, accP[nt]);
            }
        }
        const int i0 = 16 * w + quad * 4;
        float cj[4];
        #pragma unroll
        for (int nt = 0; nt < 4; ++nt) cj[nt] = __shfl(x, 16 * nt + m16, 64);
        #pragma unroll
        for (int r = 0; r < 4; ++r) {
            const float ci = __shfl(x, i0 + r, 64);
            #pragma unroll
            for (int nt = 0; nt < 4; ++nt) {
                const int j = 16 * nt + m16;
                pv[nt][r] = (i0 + r >= j) ? accP[nt][r] * expf(ci - cj[nt]) : 0.f;
            }
        }
    }

    // ---- GEMM3: updT[e][d] = sum_i v[i][e]*dte[i]*k[i][d]; store bf16 ----
    {
        f32x4 accU[2][8] = {};
        #pragma unroll
        for (int ks = 0; ks < 2; ++ks) {
            const bf16x8 a0 = *(const bf16x8*)&s_vt[(32 * w      + m16) * STR + quad * 8 + ks * 32];
            const bf16x8 a1 = *(const bf16x8*)&s_vt[(32 * w + 16 + m16) * STR + quad * 8 + ks * 32];
            #pragma unroll
            for (int nt = 0; nt < 8; ++nt) {
                const bf16x8 bf = *(const bf16x8*)&s_kt[(16 * nt + m16) * STR + quad * 8 + ks * 32];
                accU[0][nt] = MFMA(a0, bf, accU[0][nt]);
                accU[1][nt] = MFMA(a1, bf, accU[1][nt]);
            }
        }
        unsigned short* ub = upd + (size_t)blk * Dp * Dp;
        #pragma unroll
        for (int mt = 0; mt < 2; ++mt) {
            const int e0 = 32 * w + 16 * mt + quad * 4;
            #pragma unroll
            for (int nt = 0; nt < 8; ++nt) {
                const int d = 16 * nt + m16;
                #pragma unroll
                for (int r = 0; r < 4; ++r)
                    ub[(size_t)(e0 + r) * Dp + d] = f2bf(accU[mt][nt][r]);
            }
        }
    }
    __syncthreads();   // all waves done reading s_k -> safe to overlay P

    // P -> s_k region (stride 72), then GEMM2 after barrier
    unsigned short* s_P = s_k;
    {
        const int i0 = 16 * w + quad * 4;
        #pragma unroll
        for (int r = 0; r < 4; ++r)
            #pragma unroll
            for (int nt = 0; nt < 4; ++nt)
                s_P[(i0 + r) * STR + 16 * nt + m16] = f2bf(pv[nt][r]);
    }
    __syncthreads();

    // ---- GEMM2: out_intra = P @ V ----
    {
        f32x4 accO[8] = {};
        #pragma unroll
        for (int ks = 0; ks < 2; ++ks) {
            const bf16x8 af = *(const bf16x8*)&s_P[(16 * w + m16) * STR + quad * 8 + ks * 32];
            #pragma unroll
            for (int nt = 0; nt < 8; ++nt) {
                const bf16x8 bf = *(const bf16x8*)&s_vt[(16 * nt + m16) * STR + quad * 8 + ks * 32];
                accO[nt] = MFMA(af, bf, accO[nt]);
            }
        }
        const int i0 = 16 * w + quad * 4;
        #pragma unroll
        for (int nt = 0; nt < 8; ++nt) {
            const int d = 16 * nt + m16;
            #pragma unroll
            for (int r = 0; r < 4; ++r)
                out[base + (size_t)(i0 + r) * Dp + d] = accO[nt][r];
        }
    }
}

// ---------------------------------------------------------------------------
// Kernel B: sequential inter-chunk scan over bf16 states, fp32 accumulation,
// depth-2 prefetch. In-place: slot c read (updT_c) -> overwritten w/ PRE-state.
// ---------------------------------------------------------------------------
__global__ __launch_bounds__(256) void gdn_scan(
    unsigned short* __restrict__ upd, const float* __restrict__ tot_buf)
{
    const int g = blockIdx.x >> 4, slab = blockIdx.x & 15, tid = threadIdx.x;
    __shared__ float s_e[NCp];
    if (tid < NCp) s_e[tid] = expf(tot_buf[g * NCp + tid]);
    __syncthreads();
    // chunk state = 8192 u32; this thread owns u32 [slab*512+tid] and +256
    unsigned* b = (unsigned*)upd + (size_t)g * NCp * 8192 + slab * 512 + tid;
    float st0 = 0.f, st1 = 0.f, st2 = 0.f, st3 = 0.f;
    unsigned u0a = b[0],    u1a = b[256];
    unsigned u0b = b[8192], u1b = b[8192 + 256];
    for (int cc = 0; cc < NCp; ++cc) {
        unsigned n0 = 0, n1 = 0;
        if (cc < NCp - 2) {
            n0 = b[(size_t)(cc + 2) * 8192];
            n1 = b[(size_t)(cc + 2) * 8192 + 256];
        }
        const float e = s_e[cc];
        b[(size_t)cc * 8192]       = pack2(st0, st1);
        b[(size_t)cc * 8192 + 256] = pack2(st2, st3);
        st0 = st0 * e + bflo(u0a);
        st1 = st1 * e + bfhi(u0a);
        st2 = st2 * e + bflo(u1a);
        st3 = st3 * e + bfhi(u1a);
        u0a = u0b; u1a = u1b; u0b = n0; u1b = n1;
    }
}

// ---------------------------------------------------------------------------
// Kernel C: out[i][e] += dfs[i] * sum_d q[i][d] * S_c[d][e].  Zero LDS:
// q-frags from global w/ dfs folded in; stateT bf16 B-frags straight from
// global (16B loads, each block reads its own 32 KB once).
// ---------------------------------------------------------------------------
__global__ __launch_bounds__(256) void gdn_inter(
    const float* __restrict__ q, const unsigned short* __restrict__ state,
    const float* __restrict__ dfs_buf, float* __restrict__ out)
{
    const int blk = blockIdx.x, g = blk >> 6, c = blk & 63;
    const int tid = threadIdx.x, lane = tid & 63, w = tid >> 6;
    const int m16 = lane & 15, quad = lane >> 4;
    const size_t base  = ((size_t)g * Sp + (size_t)c * BTp) * Dp;
    const size_t bbase = (size_t)g * Sp + (size_t)c * BTp;
    const unsigned short* sb = state + (size_t)blk * Dp * Dp;

    const float scale = dfs_buf[bbase + 16 * w + m16];
    bf16x8 qf[4];
    const float* qrow = q + base + (size_t)(16 * w + m16) * Dp + quad * 8;
    #pragma unroll
    for (int ks = 0; ks < 4; ++ks) {
        const float4 a = *(const float4*)(qrow + ks * 32);
        const float4 b = *(const float4*)(qrow + ks * 32 + 4);
        union { bf16x8 v; unsigned ui[4]; } t;
        t.ui[0] = pack2(a.x * scale, a.y * scale);
        t.ui[1] = pack2(a.z * scale, a.w * scale);
        t.ui[2] = pack2(b.x * scale, b.y * scale);
        t.ui[3] = pack2(b.z * scale, b.w * scale);
        qf[ks] = t.v;
    }

    f32x4 acc[8] = {};
    #pragma unroll
    for (int ks = 0; ks < 4; ++ks) {
        #pragma unroll
        for (int nt = 0; nt < 8; ++nt) {
            const bf16x8 bf = *(const bf16x8*)(sb + (16 * nt + m16) * Dp + quad * 8 + ks * 32);
            acc[nt] = MFMA(qf[ks], bf, acc[nt]);
        }
    }
    const int i0 = 16 * w + quad * 4;
    #pragma unroll
    for (int nt = 0; nt < 8; ++nt) {
        const int e = 16 * nt + m16;
        #pragma unroll
        for (int r = 0; r < 4; ++r)
            out[base + (size_t)(i0 + r) * Dp + e] += acc[nt][r];
    }
}

// ---------------------------------------------------------------------------
extern "C" void kernel_launch(void* const* d_in, const int* in_sizes, int n_in,
                              void* d_out, int out_size, void* d_ws, size_t ws_size,
                              hipStream_t stream) {
    const float* q    = (const float*)d_in[0];
    const float* k    = (const float*)d_in[1];
    const float* v    = (const float*)d_in[2];
    const float* beta = (const float*)d_in[3];
    float* out = (float*)d_out;

    unsigned short* upd = (unsigned short*)d_ws;             // G*NC*D*D bf16 (updT/stateT)
    float* tot_buf = (float*)(upd + (size_t)Gp * NCp * Dp * Dp);
    float* dfs_buf = tot_buf + Gp * NCp;

    gdn_intra<<<Gp * NCp, 256, 0, stream>>>(q, k, v, beta, out, upd, tot_buf, dfs_buf);
    gdn_scan <<<Gp * 16, 256, 0, stream>>>(upd, tot_buf);
    gdn_inter<<<Gp * NCp, 256, 0, stream>>>(q, upd, dfs_buf, out);
}

// Round 4
// 314.824 us; speedup vs baseline: 2.2464x; 1.0375x over previous
//
#include <hip/hip_runtime.h>
#include <hip/hip_bf16.h>
#include <math.h>

// Problem constants: B=4,H=8,S=4096,D=128,BT=64
#define Gp  32      // B*H
#define Sp  4096
#define Dp  128
#define BTp 64
#define NCp 64      // S/BT

typedef __attribute__((ext_vector_type(8))) short bf16x8;
typedef __attribute__((ext_vector_type(4))) float f32x4;

#define MFMA(a,b,c) __builtin_amdgcn_mfma_f32_16x16x32_bf16((a),(b),(c),0,0,0)

#define STR 72    // transposed buffers (vt,kt) and P row stride, bf16 elems

__device__ inline unsigned pack2(float lo, float hi) {
    __hip_bfloat162 h = __float22bfloat162_rn(make_float2(lo, hi));  // v_cvt_pk_bf16_f32 on gfx950
    union { __hip_bfloat162 v; unsigned u; } t; t.v = h; return t.u;
}
__device__ inline unsigned short f2bf(float x) {
    union { float f; unsigned u; } u; u.f = x;
    unsigned r = u.u + 0x7fffu + ((u.u >> 16) & 1u);  // RNE
    return (unsigned short)(r >> 16);
}
__device__ inline float bflo(unsigned u) { union { unsigned u; float f; } t; t.u = u << 16; return t.f; }
__device__ inline float bfhi(unsigned u) { union { unsigned u; float f; } t; t.u = u & 0xffff0000u; return t.f; }

// ---------------------------------------------------------------------------
// Kernel A: intra-chunk output + transposed per-chunk state term (updT, bf16).
// 256 threads, LDS = 52 KB -> 3 blocks/CU.
// s_k XOR-swizzled: elem (i,d) at i*128 + ((d>>3 ^ (i&15))<<3) + (d&7)
// ---------------------------------------------------------------------------
__global__ __launch_bounds__(256, 3) void gdn_intra(
    const float* __restrict__ q, const float* __restrict__ k,
    const float* __restrict__ v, const float* __restrict__ beta,
    float* __restrict__ out, unsigned short* __restrict__ upd,
    float* __restrict__ tot_buf, float* __restrict__ dfs_buf)
{
    __shared__ unsigned short s_k [64 * 128];   // swizzled; P overlays after GEMM1
    __shared__ unsigned short s_vt[128 * STR];  // v^T  [d][i]
    __shared__ unsigned short s_kt[128 * STR];  // (k*dte)^T [d][i]

    const int blk = blockIdx.x, g = blk >> 6, c = blk & 63;
    const int tid = threadIdx.x, lane = tid & 63, w = tid >> 6;
    const int m16 = lane & 15, quad = lane >> 4;
    const size_t base  = ((size_t)g * Sp + (size_t)c * BTp) * Dp;
    const size_t bbase = (size_t)g * Sp + (size_t)c * BTp;

    // every wave redundantly computes the 64-lane log-beta prefix (no LDS dep)
    float x = logf(beta[bbase + lane] + 1e-6f);
    #pragma unroll
    for (int off = 1; off < 64; off <<= 1) {
        float n = __shfl_up(x, off, 64);
        if (lane >= off) x += n;
    }
    const float tot = __shfl(x, 63, 64);
    const float dte_own = expf(tot - x);          // lane L holds dte[L]
    if (tid < 64) dfs_buf[bbase + lane] = expf(x);
    if (tid == 63) tot_buf[g * NCp + c] = tot;

    // q A-fragments straight from global (wave-exclusive rows 16w..16w+15)
    bf16x8 qf[4];
    {
        const float* qrow = q + base + (size_t)(16 * w + m16) * Dp + quad * 8;
        #pragma unroll
        for (int ks = 0; ks < 4; ++ks) {
            const float4 a = *(const float4*)(qrow + ks * 32);
            const float4 b = *(const float4*)(qrow + ks * 32 + 4);
            union { bf16x8 v; unsigned ui[4]; } t;
            t.ui[0] = pack2(a.x, a.y); t.ui[1] = pack2(a.z, a.w);
            t.ui[2] = pack2(b.x, b.y); t.ui[3] = pack2(b.z, b.w);
            qf[ks] = t.v;
        }
    }

    // stage k -> s_k (swizzled): float4 loads, 8B LDS writes
    #pragma unroll
    for (int it = 0; it < 8; ++it) {
        const int idx = (it * 256 + tid) * 4;      // elem 0..8191, mult of 4
        const int i = idx >> 7, d = idx & 127;     // d multiple of 4
        const float4 kv = *(const float4*)(k + base + (size_t)i * Dp + d);
        const int ad = i * 128 + (((d >> 3) ^ (i & 15)) << 3) + (d & 7);
        uint2 pw; pw.x = pack2(kv.x, kv.y); pw.y = pack2(kv.z, kv.w);
        *(uint2*)&s_k[ad] = pw;
    }
    // stage v^T and (k*dte)^T: float2 loads, 4 elems/thread-iter
    #pragma unroll
    for (int it = 0; it < 8; ++it) {
        const int u = it * 256 + tid;              // 0..2047
        const int d = (u & 63) * 2, i = (u >> 6) * 2;   // d even, i even (wave-uniform i)
        const float dte0 = __shfl(dte_own, i, 64);
        const float dte1 = __shfl(dte_own, i + 1, 64);
        const float2 va = *(const float2*)(v + base + (size_t)i * Dp + d);
        const float2 vb = *(const float2*)(v + base + (size_t)(i + 1) * Dp + d);
        const float2 ka = *(const float2*)(k + base + (size_t)i * Dp + d);
        const float2 kb = *(const float2*)(k + base + (size_t)(i + 1) * Dp + d);
        *(unsigned*)&s_vt[d * STR + i]       = pack2(va.x, vb.x);
        *(unsigned*)&s_vt[(d + 1) * STR + i] = pack2(va.y, vb.y);
        *(unsigned*)&s_kt[d * STR + i]       = pack2(ka.x * dte0, kb.x * dte1);
        *(unsigned*)&s_kt[(d + 1) * STR + i] = pack2(ka.y * dte0, kb.y * dte1);
    }
    __syncthreads();

    // ---- GEMM1: P = Q @ K^T, epilogue (mask+decay) kept in registers ----
    float pv[4][4];
    {
        f32x4 accP[4] = {};
        #pragma unroll
        for (int ks = 0; ks < 4; ++ks) {
            #pragma unroll
            for (int nt = 0; nt < 4; ++nt) {
                const int j = 16 * nt + m16;
                const bf16x8 bf = *(const bf16x8*)&s_k[j * 128 + (((quad + 4 * ks) ^ m16) << 3)];
                accP[nt] = MFMA(qf[ks], bf, accP[nt]);
            }
        }
        const int i0 = 16 * w + quad * 4;
        float cj[4];
        #pragma unroll
        for (int nt = 0; nt < 4; ++nt) cj[nt] = __shfl(x, 16 * nt + m16, 64);
        #pragma unroll
        for (int r = 0; r < 4; ++r) {
            const float ci = __shfl(x, i0 + r, 64);
            #pragma unroll
            for (int nt = 0; nt < 4; ++nt) {
                const int j = 16 * nt + m16;
                pv[nt][r] = (i0 + r >= j) ? accP[nt][r] * expf(ci - cj[nt]) : 0.f;
            }
        }
    }

    // ---- GEMM3: updT[e][d] = sum_i v[i][e]*dte[i]*k[i][d]; store bf16 ----
    {
        f32x4 accU[2][8] = {};
        #pragma unroll
        for (int ks = 0; ks < 2; ++ks) {
            const bf16x8 a0 = *(const bf16x8*)&s_vt[(32 * w      + m16) * STR + quad * 8 + ks * 32];
            const bf16x8 a1 = *(const bf16x8*)&s_vt[(32 * w + 16 + m16) * STR + quad * 8 + ks * 32];
            #pragma unroll
            for (int nt = 0; nt < 8; ++nt) {
                const bf16x8 bf = *(const bf16x8*)&s_kt[(16 * nt + m16) * STR + quad * 8 + ks * 32];
                accU[0][nt] = MFMA(a0, bf, accU[0][nt]);
                accU[1][nt] = MFMA(a1, bf, accU[1][nt]);
            }
        }
        unsigned short* ub = upd + (size_t)blk * Dp * Dp;
        #pragma unroll
        for (int mt = 0; mt < 2; ++mt) {
            const int e0 = 32 * w + 16 * mt + quad * 4;
            #pragma unroll
            for (int nt = 0; nt < 8; ++nt) {
                const int d = 16 * nt + m16;
                #pragma unroll
                for (int r = 0; r < 4; ++r)
                    ub[(size_t)(e0 + r) * Dp + d] = f2bf(accU[mt][nt][r]);
            }
        }
    }
    __syncthreads();   // all waves done reading s_k -> safe to overlay P

    // P -> s_k region (stride 72), then GEMM2 after barrier
    unsigned short* s_P = s_k;
    {
        const int i0 = 16 * w + quad * 4;
        #pragma unroll
        for (int r = 0; r < 4; ++r)
            #pragma unroll
            for (int nt = 0; nt < 4; ++nt)
                s_P[(i0 + r) * STR + 16 * nt + m16] = f2bf(pv[nt][r]);
    }
    __syncthreads();

    // ---- GEMM2: out_intra = P @ V ----
    {
        f32x4 accO[8] = {};
        #pragma unroll
        for (int ks = 0; ks < 2; ++ks) {
            const bf16x8 af = *(const bf16x8*)&s_P[(16 * w + m16) * STR + quad * 8 + ks * 32];
            #pragma unroll
            for (int nt = 0; nt < 8; ++nt) {
                const bf16x8 bf = *(const bf16x8*)&s_vt[(16 * nt + m16) * STR + quad * 8 + ks * 32];
                accO[nt] = MFMA(af, bf, accO[nt]);
            }
        }
        const int i0 = 16 * w + quad * 4;
        #pragma unroll
        for (int nt = 0; nt < 8; ++nt) {
            const int d = 16 * nt + m16;
            #pragma unroll
            for (int r = 0; r < 4; ++r)
                out[base + (size_t)(i0 + r) * Dp + d] = accO[nt][r];
        }
    }
}

// ---------------------------------------------------------------------------
// Kernel B: sequential inter-chunk scan over bf16 states, fp32 accumulation.
// uint4 (8 bf16) per thread per chunk, depth-4 prefetch. In-place: slot c is
// read (updT_c) then overwritten with the PRE-chunk state.
// 512 blocks (32g x 16 slabs) x 128 threads.
// ---------------------------------------------------------------------------
__global__ __launch_bounds__(128) void gdn_scan(
    unsigned short* __restrict__ upd, const float* __restrict__ tot_buf)
{
    const int g = blockIdx.x >> 4, slab = blockIdx.x & 15, tid = threadIdx.x;
    __shared__ float s_e[NCp];
    if (tid < NCp) s_e[tid] = expf(tot_buf[g * NCp + tid]);
    __syncthreads();
    // per chunk-state: 16384 bf16 = 2048 uint4; chunk stride = 2048 uint4
    uint4* b = (uint4*)(upd + (size_t)g * NCp * Dp * Dp) + slab * 128 + tid;
    float s0 = 0.f, s1 = 0.f, s2 = 0.f, s3 = 0.f;
    float s4 = 0.f, s5 = 0.f, s6 = 0.f, s7 = 0.f;
    uint4 pf[4];
    #pragma unroll
    for (int j = 0; j < 4; ++j) pf[j] = b[(size_t)j * 2048];
    #pragma unroll
    for (int cc = 0; cc < NCp; ++cc) {
        const uint4 cur = pf[cc & 3];
        if (cc + 4 < NCp) pf[cc & 3] = b[(size_t)(cc + 4) * 2048];
        const float e = s_e[cc];
        uint4 stq;
        stq.x = pack2(s0, s1); stq.y = pack2(s2, s3);
        stq.z = pack2(s4, s5); stq.w = pack2(s6, s7);
        b[(size_t)cc * 2048] = stq;
        s0 = s0 * e + bflo(cur.x); s1 = s1 * e + bfhi(cur.x);
        s2 = s2 * e + bflo(cur.y); s3 = s3 * e + bfhi(cur.y);
        s4 = s4 * e + bflo(cur.z); s5 = s5 * e + bfhi(cur.z);
        s6 = s6 * e + bflo(cur.w); s7 = s7 * e + bfhi(cur.w);
    }
}

// ---------------------------------------------------------------------------
// Kernel C: out[i][e] += dfs[i] * sum_d q[i][d] * S_c[d][e].  Zero LDS.
// out-tile (+= operand) preloaded BEFORE the MFMA loop; state B-frags read
// straight from global in batches of 8 so loads stay in flight.
// ---------------------------------------------------------------------------
__global__ __launch_bounds__(256) void gdn_inter(
    const float* __restrict__ q, const unsigned short* __restrict__ state,
    const float* __restrict__ dfs_buf, float* __restrict__ out)
{
    const int blk = blockIdx.x, g = blk >> 6, c = blk & 63;
    const int tid = threadIdx.x, lane = tid & 63, w = tid >> 6;
    const int m16 = lane & 15, quad = lane >> 4;
    const size_t base  = ((size_t)g * Sp + (size_t)c * BTp) * Dp;
    const size_t bbase = (size_t)g * Sp + (size_t)c * BTp;
    const unsigned short* sb = state + (size_t)blk * Dp * Dp;
    const int i0 = 16 * w + quad * 4;

    const float scale = dfs_buf[bbase + 16 * w + m16];
    bf16x8 qf[4];
    const float* qrow = q + base + (size_t)(16 * w + m16) * Dp + quad * 8;
    #pragma unroll
    for (int ks = 0; ks < 4; ++ks) {
        const float4 a = *(const float4*)(qrow + ks * 32);
        const float4 b = *(const float4*)(qrow + ks * 32 + 4);
        union { bf16x8 v; unsigned ui[4]; } t;
        t.ui[0] = pack2(a.x * scale, a.y * scale);
        t.ui[1] = pack2(a.z * scale, a.w * scale);
        t.ui[2] = pack2(b.x * scale, b.y * scale);
        t.ui[3] = pack2(b.z * scale, b.w * scale);
        qf[ks] = t.v;
    }

    // preload the += operand while MFMAs run
    float ov[8][4];
    #pragma unroll
    for (int nt = 0; nt < 8; ++nt)
        #pragma unroll
        for (int r = 0; r < 4; ++r)
            ov[nt][r] = out[base + (size_t)(i0 + r) * Dp + 16 * nt + m16];

    f32x4 acc[8] = {};
    #pragma unroll
    for (int ks = 0; ks < 4; ++ks) {
        bf16x8 bfr[8];
        #pragma unroll
        for (int nt = 0; nt < 8; ++nt)
            bfr[nt] = *(const bf16x8*)(sb + (16 * nt + m16) * Dp + quad * 8 + ks * 32);
        #pragma unroll
        for (int nt = 0; nt < 8; ++nt)
            acc[nt] = MFMA(qf[ks], bfr[nt], acc[nt]);
    }
    #pragma unroll
    for (int nt = 0; nt < 8; ++nt) {
        const int e = 16 * nt + m16;
        #pragma unroll
        for (int r = 0; r < 4; ++r)
            out[base + (size_t)(i0 + r) * Dp + e] = ov[nt][r] + acc[nt][r];
    }
}

// ---------------------------------------------------------------------------
extern "C" void kernel_launch(void* const* d_in, const int* in_sizes, int n_in,
                              void* d_out, int out_size, void* d_ws, size_t ws_size,
                              hipStream_t stream) {
    const float* q    = (const float*)d_in[0];
    const float* k    = (const float*)d_in[1];
    const float* v    = (const float*)d_in[2];
    const float* beta = (const float*)d_in[3];
    float* out = (float*)d_out;

    unsigned short* upd = (unsigned short*)d_ws;             // G*NC*D*D bf16 (updT/stateT)
    float* tot_buf = (float*)(upd + (size_t)Gp * NCp * Dp * Dp);
    float* dfs_buf = tot_buf + Gp * NCp;

    gdn_intra<<<Gp * NCp, 256, 0, stream>>>(q, k, v, beta, out, upd, tot_buf, dfs_buf);
    gdn_scan <<<Gp * 16, 128, 0, stream>>>(upd, tot_buf);
    gdn_inter<<<Gp * NCp, 256, 0, stream>>>(q, upd, dfs_buf, out);
}